// Round 8
// baseline (3283.287 us; speedup 1.0000x reference)
//
#include <hip/hip_runtime.h>
#include <math.h>

// Problem shape (fixed by the harness): logits [1, T, U, D]
#define TDIM 2000
#define UDIM 32
#define DDIM 4096
#define NROWS (TDIM * UDIM)   // 64000 producer blocks
#define NSTEP 2032            // anti-diagonals n in [0,2032); 2032 = 127*16
#define NPAD  2080            // padded diagonal allocation (ring loads reach 2063)

// ---------------------------------------------------------------------------
// shfl_up(x,1) via DPP wave_shr:1 — pure VALU lane shift (r4: ds_bpermute's
// DS round-trip serializes the recurrence). Lane 0 keeps its own value —
// the u==0 override handles it. Data only flows to HIGHER lanes, so garbage
// in lanes >= 32 (they read past the 32-wide diagonal) never reaches lane tl.
// ---------------------------------------------------------------------------
__device__ __forceinline__ int dpp_up1_i(int x) {
    return __builtin_amdgcn_update_dpp(x, x, 0x138, 0xf, 0xf, false);
}
__device__ __forceinline__ float dpp_up1_f(float x) {
    return __int_as_float(dpp_up1_i(__float_as_int(x)));
}

// ---------------------------------------------------------------------------
// Fused producer-consumer kernel.
// Producers (blocks 0..NROWS-1): per (t,u) row of D=4096 logits, log-softmax
// at d=0 (blank) and d=tgt[u] (emit) into the diagonalized interleaved
// layout dD[n][u] = (blk[n-1-u][u], emit[n-u][u-1]), then RELEASE-publish:
// plain stores -> __threadfence() -> atomicAdd(cnt[n],1).
// Consumer (block NROWS): single-wave anti-diagonal DP. Per 16-diagonal
// window: ACQUIRE (device-scope atomic poll until cnt[n]==expect(n), then
// __threadfence()) placed 2 ring-blocks ahead of consumption, so the fence
// never drains young loads (r2/r3: no vmcnt(0) on the critical path).
// Overlap makes total ~= max(producer HBM time, consumer catch-up).
// ---------------------------------------------------------------------------
__global__ __launch_bounds__(256) void k_fused(
    const float* __restrict__ logits, const int* __restrict__ tgt,
    float* __restrict__ dD, unsigned* __restrict__ cnt,
    const int* __restrict__ tlenp, float* __restrict__ out)
{
    __shared__ float2 lds_out[NSTEP + 64];   // consumer: outputs + trash slots
    __shared__ float redm[4];
    __shared__ float reds[4];

    if (blockIdx.x < NROWS) {
        // ============================ producer ============================
        const int r = blockIdx.x;              // r = t*UDIM + u
        const int t = r >> 5;
        const int u = r & (UDIM - 1);
        const float* row = logits + (size_t)r * DDIM;
        const float4* row4 = reinterpret_cast<const float4*>(row);
        const int tid = threadIdx.x;

        float4 x0 = row4[tid];
        float4 x1 = row4[tid + 256];
        float4 x2 = row4[tid + 512];
        float4 x3 = row4[tid + 768];

        float m = fmaxf(fmaxf(fmaxf(x0.x, x0.y), fmaxf(x0.z, x0.w)),
                   fmaxf(fmaxf(fmaxf(x1.x, x1.y), fmaxf(x1.z, x1.w)),
                    fmaxf(fmaxf(fmaxf(x2.x, x2.y), fmaxf(x2.z, x2.w)),
                          fmaxf(fmaxf(x3.x, x3.y), fmaxf(x3.z, x3.w)))));
        #pragma unroll
        for (int off = 32; off > 0; off >>= 1)
            m = fmaxf(m, __shfl_xor(m, off));

        const int wid = tid >> 6, lane = tid & 63;
        if (lane == 0) redm[wid] = m;
        __syncthreads();
        m = fmaxf(fmaxf(redm[0], redm[1]), fmaxf(redm[2], redm[3]));

        float s = 0.f;
        s += expf(x0.x - m) + expf(x0.y - m) + expf(x0.z - m) + expf(x0.w - m);
        s += expf(x1.x - m) + expf(x1.y - m) + expf(x1.z - m) + expf(x1.w - m);
        s += expf(x2.x - m) + expf(x2.y - m) + expf(x2.z - m) + expf(x2.w - m);
        s += expf(x3.x - m) + expf(x3.y - m) + expf(x3.z - m) + expf(x3.w - m);
        #pragma unroll
        for (int off = 32; off > 0; off >>= 1)
            s += __shfl_xor(s, off);
        if (lane == 0) reds[wid] = s;
        __syncthreads();

        if (tid == 0) {
            float tot = (reds[0] + reds[1]) + (reds[2] + reds[3]);
            float l = logf(tot);
            float b = (x0.x - m) - l;            // log_softmax at d=0
            float e = (row[tgt[u]] - m) - l;     // log_softmax at d=tgt[u]
            const int n = t + u + 1;             // owned diagonal slot
            dD[(n * UDIM + u) * 2] = b;                  // .x of slot (n,u)
            if (u < UDIM - 1)
                dD[(n * UDIM + u + 1) * 2 + 1] = e;      // .y of slot (n,u+1)
            __threadfence();                     // release: data before flag
            atomicAdd(&cnt[n], 1u);              // device-scope publish
        }
        return;
    }

    // ============================ consumer ============================
    const int u  = (int)threadIdx.x;
    const int tl = tlenp[0];                     // = 31

    if (u < 64) {
        const bool is_tl = (u == tl);
        const int trash = NSTEP + u;
        const float2* dj = (const float2*)dD;

        // expect(n) = # producer rows on diagonal n
        //           = max(0, min(31,n-1) - max(0,n-2000) + 1)
        // Acquire-poll diagonals [0,32) before prologue ring loads.
        {
            int n_ = u & 31;
            int hi_ = min(31, n_ - 1);
            int lo_ = max(0, n_ - 2000);
            unsigned exp_ = (unsigned)max(0, hi_ - lo_ + 1);
            if (exp_) {
                while (__hip_atomic_load(&cnt[n_], __ATOMIC_RELAXED,
                                         __HIP_MEMORY_SCOPE_AGENT) < exp_) {}
            }
            __threadfence();   // acquire: invalidate stale L1/L2 before loads
        }

        float a = 0.f;         // alpha of this lane's previous cell (t-1,u)
        int   p = 1;           // packed start*4096 + total of that cell

        float2 q0,q1,q2,q3,q4,q5,q6,q7,q8,q9,q10,q11,q12,q13,q14,q15,
               q16,q17,q18,q19,q20,q21,q22,q23,q24,q25,q26,q27,q28,q29,q30,q31;
        q0  = dj[ 0*UDIM+u]; q1  = dj[ 1*UDIM+u]; q2  = dj[ 2*UDIM+u]; q3  = dj[ 3*UDIM+u];
        q4  = dj[ 4*UDIM+u]; q5  = dj[ 5*UDIM+u]; q6  = dj[ 6*UDIM+u]; q7  = dj[ 7*UDIM+u];
        q8  = dj[ 8*UDIM+u]; q9  = dj[ 9*UDIM+u]; q10 = dj[10*UDIM+u]; q11 = dj[11*UDIM+u];
        q12 = dj[12*UDIM+u]; q13 = dj[13*UDIM+u]; q14 = dj[14*UDIM+u]; q15 = dj[15*UDIM+u];
        q16 = dj[16*UDIM+u]; q17 = dj[17*UDIM+u]; q18 = dj[18*UDIM+u]; q19 = dj[19*UDIM+u];
        q20 = dj[20*UDIM+u]; q21 = dj[21*UDIM+u]; q22 = dj[22*UDIM+u]; q23 = dj[23*UDIM+u];
        q24 = dj[24*UDIM+u]; q25 = dj[25*UDIM+u]; q26 = dj[26*UDIM+u]; q27 = dj[27*UDIM+u];
        q28 = dj[28*UDIM+u]; q29 = dj[29*UDIM+u]; q30 = dj[30*UDIM+u]; q31 = dj[31*UDIM+u];
        const float2* pref = dj + 32 * UDIM + u; // loads target diagonal n0+32+J
        int n0 = 0;

// Acquire-poll the NEXT prefetch window [n0+32, n0+48), then fence. At this
// point the youngest outstanding ring loads are >=16 steps old -> the
// fence's vmcnt drain is cheap (r2/r3 lessons preserved).
#define POLLF do {                                                    \
        int pn_ = n0 + 32 + (u & 15);                                 \
        int hi_ = min(31, pn_ - 1);                                   \
        int lo_ = max(0, pn_ - 2000);                                 \
        unsigned exp_ = (unsigned)max(0, hi_ - lo_ + 1);              \
        if (exp_) {                                                   \
            while (__hip_atomic_load(&cnt[pn_], __ATOMIC_RELAXED,     \
                                     __HIP_MEMORY_SCOPE_AGENT) < exp_) {} \
        }                                                             \
        __threadfence();                                              \
    } while (0)

// One wavefront step. CUR = step n's operands (loaded 32 steps ago); NXT =
// step n+1's. bt=NXT.x is blk[t][tl] for lane tl — register read, no load.
// G: compile-time t>=1 guard, needed only for n < 64.
#define STEP(J, G, CUR, NXT) do {                                     \
        const int n_ = n0 + (J);                                      \
        const int t_ = n_ - u;                                        \
        float aL_ = dpp_up1_f(a);                                     \
        int   pL_ = dpp_up1_i(p);                                     \
        float fla_ = a + CUR.x;                                       \
        if (G) fla_ = (t_ >= 1) ? fla_ : -INFINITY;                   \
        float fd_ = aL_ + CUR.y;                                      \
        float bt_ = NXT.x;                                            \
        CUR = pref[(J) * UDIM];   /* prefetch diag n_+32, imm J*256B */ \
        bool  left_ = (fla_ >= fd_);  /* tie prefers blank */         \
        float na_ = left_ ? fla_ : fd_;                               \
        int   np_ = (left_ ? p : pL_) + 1;                            \
        if (u == 0) { na_ = 0.f; np_ = (n_ << 12) + 1; }              \
        a = na_; p = np_;                                             \
        int slot_ = (is_tl && (unsigned)t_ < (unsigned)TDIM) ? t_     \
                                                             : trash; \
        lds_out[slot_] = make_float2(a + bt_, __int_as_float(p));     \
    } while (0)

#define BLOCK_A(G) do {                                               \
        STEP(0,G,q0,q1);   STEP(1,G,q1,q2);   STEP(2,G,q2,q3);        \
        STEP(3,G,q3,q4);   STEP(4,G,q4,q5);   STEP(5,G,q5,q6);        \
        STEP(6,G,q6,q7);   STEP(7,G,q7,q8);   STEP(8,G,q8,q9);        \
        STEP(9,G,q9,q10);  STEP(10,G,q10,q11);STEP(11,G,q11,q12);     \
        STEP(12,G,q12,q13);STEP(13,G,q13,q14);STEP(14,G,q14,q15);     \
        STEP(15,G,q15,q16);                                           \
        pref += 16 * UDIM; n0 += 16;                                  \
    } while (0)

#define BLOCK_B(G) do {                                               \
        STEP(0,G,q16,q17); STEP(1,G,q17,q18); STEP(2,G,q18,q19);      \
        STEP(3,G,q19,q20); STEP(4,G,q20,q21); STEP(5,G,q21,q22);      \
        STEP(6,G,q22,q23); STEP(7,G,q23,q24); STEP(8,G,q24,q25);      \
        STEP(9,G,q25,q26); STEP(10,G,q26,q27);STEP(11,G,q27,q28);     \
        STEP(12,G,q28,q29);STEP(13,G,q29,q30);STEP(14,G,q30,q31);     \
        STEP(15,G,q31,q0);                                            \
        pref += 16 * UDIM; n0 += 16;                                  \
    } while (0)

        // blocks 0..3 (n = 0..63): guarded steps
        for (int it = 0; it < 2; ++it) {
            POLLF; BLOCK_A(1);
            POLLF; BLOCK_B(1);
        }
        // blocks 4..125 (n = 64..2015): slim steps
        for (int it = 0; it < 61; ++it) {
            POLLF; BLOCK_A(0);
            POLLF; BLOCK_B(0);
        }
        // block 126 (n = 2016..2031)
        POLLF; BLOCK_A(0);

#undef STEP
#undef BLOCK_A
#undef BLOCK_B
#undef POLLF
    }

    __syncthreads();
    // Coalesced writeout: la, start, total(+1), plus scalar out[0]=la[T-1].
    for (int t = (int)threadIdx.x; t < TDIM; t += 256) {
        float2 v = lds_out[t];
        int pp = __float_as_int(v.y);
        out[1 + t]            = v.x;
        out[1 + TDIM + t]     = (float)(pp >> 12);
        out[1 + 2 * TDIM + t] = (float)((pp & 4095) + 1);
        if (t == TDIM - 1) out[0] = v.x;
    }
}

extern "C" void kernel_launch(void* const* d_in, const int* in_sizes, int n_in,
                              void* d_out, int out_size, void* d_ws, size_t ws_size,
                              hipStream_t stream)
{
    const float* logits      = (const float*)d_in[0];
    const int*   targets     = (const int*)d_in[1];
    const int*   target_lens = (const int*)d_in[3];
    float* out = (float*)d_out;

    // ws layout: dD[NPAD*UDIM] float2 (~533 KB) | cnt[2048] uint (8 KB).
    // Unwritten dD slots keep 0xAA poison (finite) — isolated from outputs.
    float*    dD  = (float*)d_ws;
    unsigned* cnt = (unsigned*)((char*)d_ws + (size_t)NPAD * UDIM * sizeof(float2));

    hipMemsetAsync(cnt, 0, 2048 * sizeof(unsigned), stream);   // reset per launch
    k_fused<<<NROWS + 1, 256, 0, stream>>>(logits, targets, dD, cnt,
                                           target_lens, out);
}

// Round 9
// 280.993 us; speedup vs baseline: 11.6846x; 11.6846x over previous
//
#include <hip/hip_runtime.h>
#include <math.h>

// Problem shape (fixed by the harness): logits [1, T, U, D]
#define TDIM 2000
#define UDIM 32
#define DDIM 4096
#define NROWS (TDIM * UDIM)   // 64000 producer blocks
#define NSTEP 2032            // anti-diagonals n in [0,2032); 2032 = 127*16
#define NPAD  2080            // padded diagonal allocation (ring loads reach 2063)

// ---------------------------------------------------------------------------
// shfl_up(x,1) via DPP wave_shr:1 — pure VALU lane shift (r4: ds_bpermute's
// DS round-trip serializes the recurrence). Lane 0 keeps its own value —
// the u==0 override handles it.
// ---------------------------------------------------------------------------
__device__ __forceinline__ int dpp_up1_i(int x) {
    return __builtin_amdgcn_update_dpp(x, x, 0x138, 0xf, 0xf, false);
}
__device__ __forceinline__ float dpp_up1_f(float x) {
    return __int_as_float(dpp_up1_i(__float_as_int(x)));
}

// Coherence-point (MALL) access helpers — agent-scope RELAXED atomics only.
// r8 lesson: agent-scope FENCES lower to buffer_wbl2/buffer_inv (full L2
// writeback/invalidate) on multi-XCD gfx950; 64000 of them = 10x regression.
// Relaxed agent atomics instead lower to sc1 loads/stores that bypass the
// non-coherent XCD L2 and meet at MALL — no cache-maintenance ops at all.
__device__ __forceinline__ void st_agent(float* p, float v) {
    __hip_atomic_store(p, v, __ATOMIC_RELAXED, __HIP_MEMORY_SCOPE_AGENT);
}
__device__ __forceinline__ float2 ld_agent(const float2* p) {
    unsigned long long v = __hip_atomic_load(
        (const unsigned long long*)p, __ATOMIC_RELAXED,
        __HIP_MEMORY_SCOPE_AGENT);
    union { unsigned long long u; float2 f; } c; c.u = v; return c.f;
}

// ---------------------------------------------------------------------------
// Fused producer-consumer kernel, fence-free.
// Block 0 = consumer (single-wave anti-diagonal DP) — FIRST in dispatch
// order so it overlaps the producers (r8 had it last: zero overlap).
// Blocks 1..NROWS = producers: per (t,u) row, log-softmax at d=0 and
// d=tgt[u] into the diagonalized interleaved layout
//   dD[n][u] = (blk[n-1-u][u], emit[n-u][u-1]),  n = t+u+1,
// published via sc1 stores -> s_waitcnt vmcnt(0) -> relaxed atomicAdd.
// ---------------------------------------------------------------------------
__global__ __launch_bounds__(256) void k_fused(
    const float* __restrict__ logits, const int* __restrict__ tgt,
    float* __restrict__ dD, unsigned* __restrict__ cnt,
    const int* __restrict__ tlenp, float* __restrict__ out)
{
    __shared__ float2 lds_out[NSTEP + 64];   // consumer: outputs + trash slots
    __shared__ float redm[4];
    __shared__ float reds[4];

    if (blockIdx.x != 0) {
        // ============================ producer ============================
        const int r = (int)blockIdx.x - 1;     // r = t*UDIM + u
        const int t = r >> 5;
        const int u = r & (UDIM - 1);
        const float* row = logits + (size_t)r * DDIM;
        const float4* row4 = reinterpret_cast<const float4*>(row);
        const int tid = threadIdx.x;

        float4 x0 = row4[tid];
        float4 x1 = row4[tid + 256];
        float4 x2 = row4[tid + 512];
        float4 x3 = row4[tid + 768];

        float m = fmaxf(fmaxf(fmaxf(x0.x, x0.y), fmaxf(x0.z, x0.w)),
                   fmaxf(fmaxf(fmaxf(x1.x, x1.y), fmaxf(x1.z, x1.w)),
                    fmaxf(fmaxf(fmaxf(x2.x, x2.y), fmaxf(x2.z, x2.w)),
                          fmaxf(fmaxf(x3.x, x3.y), fmaxf(x3.z, x3.w)))));
        #pragma unroll
        for (int off = 32; off > 0; off >>= 1)
            m = fmaxf(m, __shfl_xor(m, off));

        const int wid = tid >> 6, lane = tid & 63;
        if (lane == 0) redm[wid] = m;
        __syncthreads();
        m = fmaxf(fmaxf(redm[0], redm[1]), fmaxf(redm[2], redm[3]));

        float s = 0.f;
        s += expf(x0.x - m) + expf(x0.y - m) + expf(x0.z - m) + expf(x0.w - m);
        s += expf(x1.x - m) + expf(x1.y - m) + expf(x1.z - m) + expf(x1.w - m);
        s += expf(x2.x - m) + expf(x2.y - m) + expf(x2.z - m) + expf(x2.w - m);
        s += expf(x3.x - m) + expf(x3.y - m) + expf(x3.z - m) + expf(x3.w - m);
        #pragma unroll
        for (int off = 32; off > 0; off >>= 1)
            s += __shfl_xor(s, off);
        if (lane == 0) reds[wid] = s;
        __syncthreads();

        if (tid == 0) {
            float tot = (reds[0] + reds[1]) + (reds[2] + reds[3]);
            float l = logf(tot);
            float b = (x0.x - m) - l;            // log_softmax at d=0
            float e = (row[tgt[u]] - m) - l;     // log_softmax at d=tgt[u]
            const int n = t + u + 1;             // owned diagonal slot
            st_agent(&dD[(n * UDIM + u) * 2], b);            // .x of (n,u)
            if (u < UDIM - 1)
                st_agent(&dD[(n * UDIM + u + 1) * 2 + 1], e);// .y of (n,u+1)
            // Order: data stores complete at coherence point BEFORE flag.
            asm volatile("s_waitcnt vmcnt(0)" ::: "memory");
            __hip_atomic_fetch_add(&cnt[n], 1u, __ATOMIC_RELAXED,
                                   __HIP_MEMORY_SCOPE_AGENT);
        }
        return;
    }

    // ============================ consumer ============================
    const int u  = (int)threadIdx.x;
    const int tl = tlenp[0];                     // = 31

    if (u < 64) {
        const bool is_tl = (u == tl);
        const int trash = NSTEP + u;
        const float2* dj = (const float2*)dD;

        // expect(n) = # producer rows on diagonal n
        //           = max(0, min(31,n-1) - max(0,n-2000) + 1)
        // Poll diagonals [0,32) before the prologue ring loads.
        {
            int n_ = u & 31;
            int hi_ = min(31, n_ - 1);
            int lo_ = max(0, n_ - 2000);
            unsigned exp_ = (unsigned)max(0, hi_ - lo_ + 1);
            if (exp_) {
                while (__hip_atomic_load(&cnt[n_], __ATOMIC_RELAXED,
                                         __HIP_MEMORY_SCOPE_AGENT) < exp_) {}
            }
            asm volatile("" ::: "memory");   // no load hoisting above the spin
        }

        float a = 0.f;         // alpha of this lane's previous cell (t-1,u)
        int   p = 1;           // packed start*4096 + total of that cell

        float2 q0,q1,q2,q3,q4,q5,q6,q7,q8,q9,q10,q11,q12,q13,q14,q15,
               q16,q17,q18,q19,q20,q21,q22,q23,q24,q25,q26,q27,q28,q29,q30,q31;
        q0  = ld_agent(dj+ 0*UDIM+u); q1  = ld_agent(dj+ 1*UDIM+u);
        q2  = ld_agent(dj+ 2*UDIM+u); q3  = ld_agent(dj+ 3*UDIM+u);
        q4  = ld_agent(dj+ 4*UDIM+u); q5  = ld_agent(dj+ 5*UDIM+u);
        q6  = ld_agent(dj+ 6*UDIM+u); q7  = ld_agent(dj+ 7*UDIM+u);
        q8  = ld_agent(dj+ 8*UDIM+u); q9  = ld_agent(dj+ 9*UDIM+u);
        q10 = ld_agent(dj+10*UDIM+u); q11 = ld_agent(dj+11*UDIM+u);
        q12 = ld_agent(dj+12*UDIM+u); q13 = ld_agent(dj+13*UDIM+u);
        q14 = ld_agent(dj+14*UDIM+u); q15 = ld_agent(dj+15*UDIM+u);
        q16 = ld_agent(dj+16*UDIM+u); q17 = ld_agent(dj+17*UDIM+u);
        q18 = ld_agent(dj+18*UDIM+u); q19 = ld_agent(dj+19*UDIM+u);
        q20 = ld_agent(dj+20*UDIM+u); q21 = ld_agent(dj+21*UDIM+u);
        q22 = ld_agent(dj+22*UDIM+u); q23 = ld_agent(dj+23*UDIM+u);
        q24 = ld_agent(dj+24*UDIM+u); q25 = ld_agent(dj+25*UDIM+u);
        q26 = ld_agent(dj+26*UDIM+u); q27 = ld_agent(dj+27*UDIM+u);
        q28 = ld_agent(dj+28*UDIM+u); q29 = ld_agent(dj+29*UDIM+u);
        q30 = ld_agent(dj+30*UDIM+u); q31 = ld_agent(dj+31*UDIM+u);
        const float2* pref = dj + 32 * UDIM + u; // loads target diag n0+32+J
        int n0 = 0;

// Poll the NEXT prefetch window [n0+32, n0+48). No fence — the sc1 data
// loads can't be stale (they bypass L2), and hardware can't issue them
// before the spin's control dependency resolves; the asm barrier stops
// compiler hoisting. Youngest outstanding ring loads are >=16 steps old.
#define POLLF do {                                                    \
        int pn_ = n0 + 32 + (u & 15);                                 \
        int hi_ = min(31, pn_ - 1);                                   \
        int lo_ = max(0, pn_ - 2000);                                 \
        unsigned exp_ = (unsigned)max(0, hi_ - lo_ + 1);              \
        if (exp_) {                                                   \
            while (__hip_atomic_load(&cnt[pn_], __ATOMIC_RELAXED,     \
                                     __HIP_MEMORY_SCOPE_AGENT) < exp_) {} \
        }                                                             \
        asm volatile("" ::: "memory");                                \
    } while (0)

// One wavefront step. CUR = step n's operands (loaded 32 steps ago); NXT =
// step n+1's. bt=NXT.x is blk[t][tl] for lane tl — register read, no load.
// G: compile-time t>=1 guard, needed only for n < 64.
#define STEP(J, G, CUR, NXT) do {                                     \
        const int n_ = n0 + (J);                                      \
        const int t_ = n_ - u;                                        \
        float aL_ = dpp_up1_f(a);                                     \
        int   pL_ = dpp_up1_i(p);                                     \
        float fla_ = a + CUR.x;                                       \
        if (G) fla_ = (t_ >= 1) ? fla_ : -INFINITY;                   \
        float fd_ = aL_ + CUR.y;                                      \
        float bt_ = NXT.x;                                            \
        CUR = ld_agent(pref + (J) * UDIM);   /* prefetch diag n_+32 */ \
        bool  left_ = (fla_ >= fd_);  /* tie prefers blank */         \
        float na_ = left_ ? fla_ : fd_;                               \
        int   np_ = (left_ ? p : pL_) + 1;                            \
        if (u == 0) { na_ = 0.f; np_ = (n_ << 12) + 1; }              \
        a = na_; p = np_;                                             \
        int slot_ = (is_tl && (unsigned)t_ < (unsigned)TDIM) ? t_     \
                                                             : trash; \
        lds_out[slot_] = make_float2(a + bt_, __int_as_float(p));     \
    } while (0)

#define BLOCK_A(G) do {                                               \
        STEP(0,G,q0,q1);   STEP(1,G,q1,q2);   STEP(2,G,q2,q3);        \
        STEP(3,G,q3,q4);   STEP(4,G,q4,q5);   STEP(5,G,q5,q6);        \
        STEP(6,G,q6,q7);   STEP(7,G,q7,q8);   STEP(8,G,q8,q9);        \
        STEP(9,G,q9,q10);  STEP(10,G,q10,q11);STEP(11,G,q11,q12);     \
        STEP(12,G,q12,q13);STEP(13,G,q13,q14);STEP(14,G,q14,q15);     \
        STEP(15,G,q15,q16);                                           \
        pref += 16 * UDIM; n0 += 16;                                  \
    } while (0)

#define BLOCK_B(G) do {                                               \
        STEP(0,G,q16,q17); STEP(1,G,q17,q18); STEP(2,G,q18,q19);      \
        STEP(3,G,q19,q20); STEP(4,G,q20,q21); STEP(5,G,q21,q22);      \
        STEP(6,G,q22,q23); STEP(7,G,q23,q24); STEP(8,G,q24,q25);      \
        STEP(9,G,q25,q26); STEP(10,G,q26,q27);STEP(11,G,q27,q28);     \
        STEP(12,G,q28,q29);STEP(13,G,q29,q30);STEP(14,G,q30,q31);     \
        STEP(15,G,q31,q0);                                            \
        pref += 16 * UDIM; n0 += 16;                                  \
    } while (0)

        // blocks 0..3 (n = 0..63): guarded steps
        for (int it = 0; it < 2; ++it) {
            POLLF; BLOCK_A(1);
            POLLF; BLOCK_B(1);
        }
        // blocks 4..125 (n = 64..2015): slim steps
        for (int it = 0; it < 61; ++it) {
            POLLF; BLOCK_A(0);
            POLLF; BLOCK_B(0);
        }
        // block 126 (n = 2016..2031)
        POLLF; BLOCK_A(0);

#undef STEP
#undef BLOCK_A
#undef BLOCK_B
#undef POLLF
    }

    __syncthreads();
    // Coalesced writeout: la, start, total(+1), plus scalar out[0]=la[T-1].
    for (int t = (int)threadIdx.x; t < TDIM; t += 256) {
        float2 v = lds_out[t];
        int pp = __float_as_int(v.y);
        out[1 + t]            = v.x;
        out[1 + TDIM + t]     = (float)(pp >> 12);
        out[1 + 2 * TDIM + t] = (float)((pp & 4095) + 1);
        if (t == TDIM - 1) out[0] = v.x;
    }
}

extern "C" void kernel_launch(void* const* d_in, const int* in_sizes, int n_in,
                              void* d_out, int out_size, void* d_ws, size_t ws_size,
                              hipStream_t stream)
{
    const float* logits      = (const float*)d_in[0];
    const int*   targets     = (const int*)d_in[1];
    const int*   target_lens = (const int*)d_in[3];
    float* out = (float*)d_out;

    // ws layout: dD[NPAD*UDIM] float2 (~533 KB) | cnt[2048] uint (8 KB).
    // Unwritten dD slots keep their (finite) contents — isolated from outputs.
    float*    dD  = (float*)d_ws;
    unsigned* cnt = (unsigned*)((char*)d_ws + (size_t)NPAD * UDIM * sizeof(float2));

    hipMemsetAsync(cnt, 0, 2048 * sizeof(unsigned), stream);   // reset per launch
    k_fused<<<NROWS + 1, 256, 0, stream>>>(logits, targets, dD, cnt,
                                           target_lens, out);
}